// Round 1
// baseline (23.102 us; speedup 1.0000x reference)
//
#include <hip/hip_runtime.h>

#define MAXV 8
#define TPB  256

// One thread = one (pred, gt) quad pair.
// Sutherland-Hodgman clip of pred quad against the 4 gt edges (gt forced CCW),
// shoelace areas, IoU, masked loss. Per-block partial sums -> d_ws, then a
// deterministic single-block finalize reduces to the scalar mean.
__global__ __launch_bounds__(TPB) void obb_pair_kernel(
    const float* __restrict__ pred, const float* __restrict__ gt,
    const int* __restrict__ image_size, const int* __restrict__ mask,
    float2* __restrict__ partial, int nper, int total)
{
    // Per-thread scatter slab for the clip output. Stride 17 floats (odd) so
    // bank = (17*lane + slot) % 32 is bijective -> only free 2-way aliasing.
    __shared__ float outbuf[TPB * 17];
    __shared__ float red_l[TPB / 64], red_m[TPB / 64];

    const int idx = blockIdx.x * TPB + threadIdx.x;
    float* ob = &outbuf[threadIdx.x * 17];

    float loss = 0.f, mval = 0.f;

    if (idx < total) {
        const int b = idx / nper;
        const float W = (float)image_size[2 * b];
        const float H = (float)image_size[2 * b + 1];

        const float4 p01 = reinterpret_cast<const float4*>(pred)[idx * 2];
        const float4 p23 = reinterpret_cast<const float4*>(pred)[idx * 2 + 1];
        const float4 g01 = reinterpret_cast<const float4*>(gt)[idx * 2];
        const float4 g23 = reinterpret_cast<const float4*>(gt)[idx * 2 + 1];

        float px[4] = {p01.x * W, p01.z * W, p23.x * W, p23.z * W};
        float py[4] = {p01.y * H, p01.w * H, p23.y * H, p23.w * H};
        float gx[4] = {g01.x * W, g01.z * W, g23.x * W, g23.z * W};
        float gy[4] = {g01.y * H, g01.w * H, g23.y * H, g23.w * H};

        // signed areas of p and g (shoelace, cnt=4)
        float ap_s = 0.f, ag_s = 0.f;
        #pragma unroll
        for (int i = 0; i < 4; ++i) {
            const int j = (i + 1) & 3;
            ap_s += px[i] * py[j] - py[i] * px[j];
            ag_s += gx[i] * gy[j] - gy[i] * gx[j];
        }
        ap_s *= 0.5f;
        ag_s *= 0.5f;

        if (ag_s < 0.f) {  // make clip polygon CCW: g = g[::-1]
            float t;
            t = gx[0]; gx[0] = gx[3]; gx[3] = t;
            t = gy[0]; gy[0] = gy[3]; gy[3] = t;
            t = gx[1]; gx[1] = gx[2]; gx[2] = t;
            t = gy[1]; gy[1] = gy[2]; gy[2] = t;
        }

        // poly registers: all reads below use compile-time indices
        float polyx[MAXV], polyy[MAXV];
        #pragma unroll
        for (int i = 0; i < 4; ++i) { polyx[i] = px[i]; polyy[i] = py[i]; }
        #pragma unroll
        for (int i = 4; i < MAXV; ++i) { polyx[i] = 0.f; polyy[i] = 0.f; }
        int cnt = 4;

        #pragma unroll
        for (int k = 0; k < 4; ++k) {
            const float ax = gx[k], ay = gy[k];
            const float bx = gx[(k + 1) & 3], by = gy[(k + 1) & 3];
            const float ex = bx - ax, ey = by - ay;

            // line distance of every poly vertex to edge a->b (left positive)
            float d[MAXV];
            #pragma unroll
            for (int i = 0; i < MAXV; ++i)
                d[i] = ex * (polyy[i] - ay) - ey * (polyx[i] - ax);

            int ocnt = 0;
            #pragma unroll
            for (int i = 0; i < MAXV; ++i) {
                const bool active = i < cnt;
                const bool nw = (i + 1) < cnt;     // next index wraps to 0?
                const float dc = d[i];
                const float dn = nw ? d[(i + 1) & 7] : d[0];
                const float nx = nw ? polyx[(i + 1) & 7] : polyx[0];
                const float ny = nw ? polyy[(i + 1) & 7] : polyy[0];
                const bool cin = dc >= 0.f;
                const bool nin = dn >= 0.f;

                if (active && cin) {               // keep current vertex
                    const int s = (ocnt < MAXV) ? ocnt : (MAXV - 1);
                    ob[s * 2]     = polyx[i];
                    ob[s * 2 + 1] = polyy[i];
                    ocnt++;
                }
                if (active && (cin != nin)) {      // edge crosses the line
                    const float denom = dc - dn;
                    const float dd = (fabsf(denom) < 1e-12f) ? 1e-12f : denom;
                    const float t = dc / dd;
                    const float ipx = polyx[i] + t * (nx - polyx[i]);
                    const float ipy = polyy[i] + t * (ny - polyy[i]);
                    const int s = (ocnt < MAXV) ? ocnt : (MAXV - 1);
                    ob[s * 2]     = ipx;
                    ob[s * 2 + 1] = ipy;
                    ocnt++;
                }
            }
            cnt = (ocnt < MAXV) ? ocnt : MAXV;
            // pull clipped polygon back into registers (fixed LDS offsets);
            // slots >= cnt are stale but never consumed (all uses mask i<cnt)
            #pragma unroll
            for (int i = 0; i < MAXV; ++i) {
                polyx[i] = ob[i * 2];
                polyy[i] = ob[i * 2 + 1];
            }
        }

        // shoelace of intersection polygon (first cnt vertices)
        float inter_s = 0.f;
        #pragma unroll
        for (int i = 0; i < MAXV; ++i) {
            if (i < cnt) {
                const bool nw = (i + 1) < cnt;
                const float nx = nw ? polyx[(i + 1) & 7] : polyx[0];
                const float ny = nw ? polyy[(i + 1) & 7] : polyy[0];
                inter_s += polyx[i] * ny - polyy[i] * nx;
            }
        }
        const float inter = fabsf(0.5f * inter_s);
        const float ap = fabsf(ap_s);
        const float ag = fabsf(ag_s);
        const float uni = ap + ag - inter;
        const float iou = (uni > 0.f) ? (inter / uni) : 0.f;
        mval = (mask[idx] != 0) ? 1.f : 0.f;
        loss = (1.f - iou) * mval;
    }

    // deterministic block reduction: wave shuffle then cross-wave LDS
    float l = loss, m = mval;
    #pragma unroll
    for (int off = 32; off > 0; off >>= 1) {
        l += __shfl_down(l, off, 64);
        m += __shfl_down(m, off, 64);
    }
    const int wid = threadIdx.x >> 6;
    const int lane = threadIdx.x & 63;
    if (lane == 0) { red_l[wid] = l; red_m[wid] = m; }
    __syncthreads();
    if (threadIdx.x == 0) {
        float L = 0.f, M = 0.f;
        #pragma unroll
        for (int w = 0; w < TPB / 64; ++w) { L += red_l[w]; M += red_m[w]; }
        partial[blockIdx.x] = make_float2(L, M);
    }
}

__global__ __launch_bounds__(256) void obb_finalize(
    const float2* __restrict__ partial, int nb, float* __restrict__ out)
{
    __shared__ double sl[256], sm[256];
    double l = 0.0, m = 0.0;
    for (int i = threadIdx.x; i < nb; i += 256) {
        const float2 v = partial[i];
        l += (double)v.x;
        m += (double)v.y;
    }
    sl[threadIdx.x] = l;
    sm[threadIdx.x] = m;
    __syncthreads();
    for (int s = 128; s > 0; s >>= 1) {
        if (threadIdx.x < s) {
            sl[threadIdx.x] += sl[threadIdx.x + s];
            sm[threadIdx.x] += sm[threadIdx.x + s];
        }
        __syncthreads();
    }
    if (threadIdx.x == 0) {
        const double nval = sm[0];
        const double mean = sl[0] / (nval > 1.0 ? nval : 1.0);
        out[0] = (nval > 0.0) ? (float)mean : 0.f;
    }
}

extern "C" void kernel_launch(void* const* d_in, const int* in_sizes, int n_in,
                              void* d_out, int out_size, void* d_ws, size_t ws_size,
                              hipStream_t stream)
{
    const float* pred = (const float*)d_in[0];   // (B,N,8) f32
    const float* gt   = (const float*)d_in[1];   // (B,N,8) f32
    const int* imsz   = (const int*)d_in[2];     // (B,2) i32
    const int* mask   = (const int*)d_in[3];     // (B,N) bool -> i32
    float* out = (float*)d_out;                  // scalar f32

    const int total = in_sizes[0] / 8;           // B*N
    const int B     = in_sizes[2] / 2;
    const int nper  = total / B;                 // N
    const int blocks = (total + TPB - 1) / TPB;

    float2* partial = (float2*)d_ws;             // blocks * 8 bytes

    obb_pair_kernel<<<blocks, TPB, 0, stream>>>(pred, gt, imsz, mask,
                                                partial, nper, total);
    obb_finalize<<<1, 256, 0, stream>>>(partial, blocks, out);
}

// Round 2
// 20.672 us; speedup vs baseline: 1.1176x; 1.1176x over previous
//
#include <hip/hip_runtime.h>

#define TPB   256
#define NSLOT 9   // float2 slots per thread slab; 9*8B=72B odd 8B-stride ->
                  // lanes 0..15 cover all 32 banks for b64 -> conflict-free

__device__ __forceinline__ float rcp_c(float denom) {
    // reference: denom -> 1e-12 when |denom| < 1e-12 (sign dropped), then divide
    const float d = (fabsf(denom) < 1e-12f) ? 1e-12f : denom;
    return __builtin_amdgcn_rcpf(d);
}

// Clip polygon (px,py,cnt) against half-plane d(x,y) = ex*y - ey*x - c0 >= 0.
// MAXIN bounds cnt at compile time (cnt after k clips is <= 4+k), so the loop
// is fully unrolled with compile-time register indices for all READS; the
// scatter WRITES go to the per-thread LDS slab `ob` (b64, conflict-free).
// LAST=true streams the shoelace area of the emitted polygon instead of
// materializing it (no LDS at all for the final clip).
template<int MAXIN, bool LAST>
__device__ __forceinline__ float clip_edge(
    float (&px)[7], float (&py)[7], int& cnt,
    const float ex, const float ey, const float c0,
    float2* __restrict__ ob)
{
    const float d0 = fmaf(ex, py[0], -fmaf(ey, px[0], c0));
    float dc = d0;
    int ocnt = 0;
    float fx = 0.f, fy = 0.f, lx = 0.f, ly = 0.f, area2 = 0.f;

    #pragma unroll
    for (int i = 0; i < MAXIN; ++i) {
        if (i >= 5) { if (__all(cnt <= i)) break; }   // dead-tail skip (wave-uniform)
        const bool active = i < cnt;
        float dn, nx, ny, draw = 0.f;
        if (i + 1 < MAXIN) {                           // compile-time branch
            draw = fmaf(ex, py[i + 1], -fmaf(ey, px[i + 1], c0));
            const bool w = (i + 1) < cnt;              // next wraps to 0?
            dn = w ? draw : d0;
            nx = w ? px[i + 1] : px[0];
            ny = w ? py[i + 1] : py[0];
        } else {
            dn = d0; nx = px[0]; ny = py[0];
        }
        const bool cin = dc >= 0.f;
        const bool nin = dn >= 0.f;

        if (active && cin) {                           // keep current vertex
            if (LAST) {
                const bool first = (ocnt == 0);
                const float t2 = lx * py[i] - ly * px[i];
                area2 += first ? 0.f : t2;
                fx = first ? px[i] : fx;  fy = first ? py[i] : fy;
                lx = px[i];  ly = py[i];
            } else {
                const int s = (ocnt < 8) ? ocnt : 8;   // slot 8 = safe dump
                ob[s] = make_float2(px[i], py[i]);
            }
            ++ocnt;
        }
        if (active && (cin != nin)) {                  // edge crosses the line
            const float t   = dc * rcp_c(dc - dn);
            const float ipx = fmaf(t, nx - px[i], px[i]);
            const float ipy = fmaf(t, ny - py[i], py[i]);
            if (LAST) {
                const bool first = (ocnt == 0);
                const float t2 = lx * ipy - ly * ipx;
                area2 += first ? 0.f : t2;
                fx = first ? ipx : fx;  fy = first ? ipy : fy;
                lx = ipx;  ly = ipy;
            } else {
                const int s = (ocnt < 8) ? ocnt : 8;
                ob[s] = make_float2(ipx, ipy);
            }
            ++ocnt;
        }
        dc = draw;  // real d[i+1]; garbage only on the final iteration (unused)
    }

    if (LAST) {
        area2 += (ocnt > 0) ? (lx * fy - ly * fx) : 0.f;  // close the polygon
        return area2;
    }

    // pull clipped polygon back into registers (fixed LDS offsets); slots
    // >= ocnt are stale but never consumed (every consumer masks i < cnt)
    constexpr int MAXOUT = (MAXIN + 1 < 7) ? (MAXIN + 1) : 7;
    #pragma unroll
    for (int i = 0; i < MAXOUT; ++i) {
        if (i >= 5) { if (__all(ocnt <= i)) break; }
        const float2 v = ob[i];
        px[i] = v.x;  py[i] = v.y;
    }
    cnt = (ocnt < MAXOUT) ? ocnt : MAXOUT;
    return 0.f;
}

__global__ __launch_bounds__(TPB) void obb_pair_kernel(
    const float4* __restrict__ pred, const float4* __restrict__ gt,
    const int* __restrict__ image_size, const int* __restrict__ mask,
    float2* __restrict__ partial, int nper, int total)
{
    __shared__ float2 slab[TPB * NSLOT];               // 18 KiB
    __shared__ float red_l[TPB / 64], red_m[TPB / 64];

    const int idx = blockIdx.x * TPB + threadIdx.x;
    float2* ob = &slab[threadIdx.x * NSLOT];

    float loss = 0.f, mval = 0.f;

    if (idx < total) {
        // batch index: wave-uniform when nper % TPB == 0 (true for B=16,N=32768)
        const int b = ((nper % TPB) == 0)
                        ? (int)(((unsigned)blockIdx.x * TPB) / (unsigned)nper)
                        : idx / nper;
        const float W = (float)image_size[2 * b];
        const float H = (float)image_size[2 * b + 1];

        const float4 p01 = pred[idx * 2], p23 = pred[idx * 2 + 1];
        const float4 g01 = gt[idx * 2],   g23 = gt[idx * 2 + 1];

        float ppx[4] = {p01.x * W, p01.z * W, p23.x * W, p23.z * W};
        float ppy[4] = {p01.y * H, p01.w * H, p23.y * H, p23.w * H};
        float gx[4]  = {g01.x * W, g01.z * W, g23.x * W, g23.z * W};
        float gy[4]  = {g01.y * H, g01.w * H, g23.y * H, g23.w * H};

        float ap_s = 0.f, ag_s = 0.f;                  // shoelace, cnt=4
        #pragma unroll
        for (int i = 0; i < 4; ++i) {
            const int j = (i + 1) & 3;
            ap_s += ppx[i] * ppy[j] - ppy[i] * ppx[j];
            ag_s += gx[i] * gy[j] - gy[i] * gx[j];
        }
        ap_s *= 0.5f;  ag_s *= 0.5f;

        if (ag_s < 0.f) {                              // force gt CCW: g[::-1]
            float t;
            t = gx[0]; gx[0] = gx[3]; gx[3] = t;  t = gy[0]; gy[0] = gy[3]; gy[3] = t;
            t = gx[1]; gx[1] = gx[2]; gx[2] = t;  t = gy[1]; gy[1] = gy[2]; gy[2] = t;
        }

        // per-edge constants: d = ex*y - ey*x - c0
        float ex[4], ey[4], c0[4];
        #pragma unroll
        for (int k = 0; k < 4; ++k) {
            const int k2 = (k + 1) & 3;
            ex[k] = gx[k2] - gx[k];
            ey[k] = gy[k2] - gy[k];
            c0[k] = ex[k] * gy[k] - ey[k] * gx[k];
        }

        float px[7], py[7];
        #pragma unroll
        for (int i = 0; i < 4; ++i) { px[i] = ppx[i]; py[i] = ppy[i]; }
        px[4] = px[5] = px[6] = 0.f;  py[4] = py[5] = py[6] = 0.f;
        int cnt = 4;

        clip_edge<4, false>(px, py, cnt, ex[0], ey[0], c0[0], ob);
        clip_edge<5, false>(px, py, cnt, ex[1], ey[1], c0[1], ob);
        clip_edge<6, false>(px, py, cnt, ex[2], ey[2], c0[2], ob);
        const float a2 = clip_edge<7, true>(px, py, cnt, ex[3], ey[3], c0[3], ob);

        const float inter = 0.5f * fabsf(a2);
        const float ap = fabsf(ap_s), ag = fabsf(ag_s);
        const float uni = ap + ag - inter;
        const float iou = (uni > 0.f) ? inter * __builtin_amdgcn_rcpf(uni) : 0.f;
        mval = (mask[idx] != 0) ? 1.f : 0.f;
        loss = (1.f - iou) * mval;
    }

    // deterministic block reduction: wave shuffle then cross-wave LDS
    float l = loss, m = mval;
    #pragma unroll
    for (int off = 32; off > 0; off >>= 1) {
        l += __shfl_down(l, off, 64);
        m += __shfl_down(m, off, 64);
    }
    const int wid  = threadIdx.x >> 6;
    const int lane = threadIdx.x & 63;
    if (lane == 0) { red_l[wid] = l; red_m[wid] = m; }
    __syncthreads();
    if (threadIdx.x == 0) {
        float L = 0.f, M = 0.f;
        #pragma unroll
        for (int w = 0; w < TPB / 64; ++w) { L += red_l[w]; M += red_m[w]; }
        partial[blockIdx.x] = make_float2(L, M);
    }
}

__global__ __launch_bounds__(256) void obb_finalize(
    const float2* __restrict__ partial, int nb, float* __restrict__ out)
{
    __shared__ double sl[256], sm[256];
    double l = 0.0, m = 0.0;
    for (int i = threadIdx.x; i < nb; i += 256) {
        const float2 v = partial[i];
        l += (double)v.x;
        m += (double)v.y;
    }
    sl[threadIdx.x] = l;
    sm[threadIdx.x] = m;
    __syncthreads();
    for (int s = 128; s > 0; s >>= 1) {
        if (threadIdx.x < s) {
            sl[threadIdx.x] += sl[threadIdx.x + s];
            sm[threadIdx.x] += sm[threadIdx.x + s];
        }
        __syncthreads();
    }
    if (threadIdx.x == 0) {
        const double nval = sm[0];
        const double mean = sl[0] / (nval > 1.0 ? nval : 1.0);
        out[0] = (nval > 0.0) ? (float)mean : 0.f;
    }
}

extern "C" void kernel_launch(void* const* d_in, const int* in_sizes, int n_in,
                              void* d_out, int out_size, void* d_ws, size_t ws_size,
                              hipStream_t stream)
{
    const float4* pred = (const float4*)d_in[0];   // (B,N,8) f32
    const float4* gt   = (const float4*)d_in[1];   // (B,N,8) f32
    const int* imsz    = (const int*)d_in[2];      // (B,2) i32
    const int* mask    = (const int*)d_in[3];      // (B,N) bool->i32
    float* out = (float*)d_out;                    // scalar f32

    const int total  = in_sizes[0] / 8;            // B*N
    const int B      = in_sizes[2] / 2;
    const int nper   = total / B;                  // N
    const int blocks = (total + TPB - 1) / TPB;

    float2* partial = (float2*)d_ws;               // blocks * 8 B

    obb_pair_kernel<<<blocks, TPB, 0, stream>>>(pred, gt, imsz, mask,
                                                partial, nper, total);
    obb_finalize<<<1, 256, 0, stream>>>(partial, blocks, out);
}

// Round 3
// 19.529 us; speedup vs baseline: 1.1830x; 1.0585x over previous
//
#include <hip/hip_runtime.h>

#define TPB 256

__device__ __forceinline__ float rcp_c(float denom) {
    // reference semantics: denom -> 1e-12 when |denom| < 1e-12, then divide
    const float d = (fabsf(denom) < 1e-12f) ? 1e-12f : denom;
    return __builtin_amdgcn_rcpf(d);
}

// Sum over the 4 edges (A->B) of CCW polygon V of (t1-t0)*cross(A,B), where
// [t0,t1] in [0,1] is the sub-interval of the edge inside the CCW clip quad
// given by lines d(X) = ex*X.y - ey*X.x - c0 >= 0.  This equals the shoelace
// line-integral of the boundary pieces of V retained inside the clip quad:
// summing both (P clipped by Q) and (Q clipped by P) gives 2*area(P∩Q).
// TIE_LE: treat d==0 as OUTSIDE (used for the Q-pass so segments lying exactly
// on P's boundary aren't double-counted).
template<bool TIE_LE>
__device__ __forceinline__ float edge_pieces(
    const float (&vx)[4], const float (&vy)[4],
    const float (&ex)[4], const float (&ey)[4], const float (&c0)[4])
{
    // distance of every vertex to every clip line, and its sign
    float d[4][4];
    bool  s[4][4];
    #pragma unroll
    for (int i = 0; i < 4; ++i)
        #pragma unroll
        for (int k = 0; k < 4; ++k) {
            d[i][k] = fmaf(ex[k], vy[i], -fmaf(ey[k], vx[i], c0[k]));
            s[i][k] = TIE_LE ? (d[i][k] <= 0.f) : (d[i][k] < 0.f);
        }

    float sum = 0.f;
    #pragma unroll
    for (int i = 0; i < 4; ++i) {
        const int j = (i + 1) & 3;
        const float cr = vx[i] * vy[j] - vy[i] * vx[j];

        float lo[4], hi[4];
        #pragma unroll
        for (int k = 0; k < 4; ++k) {
            const float dA = d[i][k], dB = d[j][k];
            const bool  sA = s[i][k], sB = s[j][k];
            const float t  = dA * rcp_c(dA - dB);       // crossing parameter
            lo[k] = sA ? (sB ? 2.f : t) : 0.f;          // entering constraint
            hi[k] = sB ? (sA ? -1.f : t) : 1.f;         // leaving constraint
        }
        const float t0 = fmaxf(fmaxf(lo[0], lo[1]), fmaxf(lo[2], lo[3]));
        const float t1 = fminf(fminf(hi[0], hi[1]), fminf(hi[2], hi[3]));
        sum = fmaf(fmaxf(t1 - t0, 0.f), cr, sum);
    }
    return sum;
}

__device__ __forceinline__ void make_lines(
    const float (&vx)[4], const float (&vy)[4],
    float (&ex)[4], float (&ey)[4], float (&c0)[4])
{
    #pragma unroll
    for (int k = 0; k < 4; ++k) {
        const int k2 = (k + 1) & 3;
        ex[k] = vx[k2] - vx[k];
        ey[k] = vy[k2] - vy[k];
        c0[k] = fmaf(ex[k], vy[k], -(ey[k] * vx[k]));
    }
}

__global__ __launch_bounds__(TPB) void obb_pair_kernel(
    const float4* __restrict__ pred, const float4* __restrict__ gt,
    const int* __restrict__ image_size, const int* __restrict__ mask,
    float2* __restrict__ partial, int nper, int total)
{
    __shared__ float red_l[TPB / 64], red_m[TPB / 64];

    const int idx = blockIdx.x * TPB + threadIdx.x;
    float loss = 0.f, mval = 0.f;

    if (idx < total) {
        // batch index: wave-uniform when nper % TPB == 0
        const int b = ((nper % TPB) == 0)
                        ? (int)(((unsigned)blockIdx.x * TPB) / (unsigned)nper)
                        : idx / nper;
        const float W = (float)image_size[2 * b];
        const float H = (float)image_size[2 * b + 1];

        const float4 p01 = pred[idx * 2], p23 = pred[idx * 2 + 1];
        const float4 g01 = gt[idx * 2],   g23 = gt[idx * 2 + 1];

        float px[4] = {p01.x * W, p01.z * W, p23.x * W, p23.z * W};
        float py[4] = {p01.y * H, p01.w * H, p23.y * H, p23.w * H};
        float gx[4] = {g01.x * W, g01.z * W, g23.x * W, g23.z * W};
        float gy[4] = {g01.y * H, g01.w * H, g23.y * H, g23.w * H};

        // signed areas (shoelace, cnt=4)
        float ap_s = 0.f, ag_s = 0.f;
        #pragma unroll
        for (int i = 0; i < 4; ++i) {
            const int j = (i + 1) & 3;
            ap_s += px[i] * py[j] - py[i] * px[j];
            ag_s += gx[i] * gy[j] - gy[i] * gx[j];
        }
        ap_s *= 0.5f;  ag_s *= 0.5f;

        // force both quads CCW (area value is orientation-invariant)
        if (ap_s < 0.f) {
            float t;
            t = px[0]; px[0] = px[3]; px[3] = t;  t = py[0]; py[0] = py[3]; py[3] = t;
            t = px[1]; px[1] = px[2]; px[2] = t;  t = py[1]; py[1] = py[2]; py[2] = t;
        }
        if (ag_s < 0.f) {
            float t;
            t = gx[0]; gx[0] = gx[3]; gx[3] = t;  t = gy[0]; gy[0] = gy[3]; gy[3] = t;
            t = gx[1]; gx[1] = gx[2]; gx[2] = t;  t = gy[1]; gy[1] = gy[2]; gy[2] = t;
        }

        // half-plane line constants for both quads
        float pex[4], pey[4], pc0[4], gex[4], gey[4], gc0[4];
        make_lines(px, py, pex, pey, pc0);
        make_lines(gx, gy, gex, gey, gc0);

        // 2*area(P∩Q) = P-edges clipped by Q + Q-edges clipped by P
        const float a2 = edge_pieces<false>(px, py, gex, gey, gc0)
                       + edge_pieces<true >(gx, gy, pex, pey, pc0);

        const float inter = 0.5f * fabsf(a2);
        const float ap = fabsf(ap_s), ag = fabsf(ag_s);
        const float uni = ap + ag - inter;
        const float iou = (uni > 0.f) ? inter * __builtin_amdgcn_rcpf(uni) : 0.f;
        mval = (mask[idx] != 0) ? 1.f : 0.f;
        loss = (1.f - iou) * mval;
    }

    // deterministic block reduction: wave shuffle then cross-wave LDS
    float l = loss, m = mval;
    #pragma unroll
    for (int off = 32; off > 0; off >>= 1) {
        l += __shfl_down(l, off, 64);
        m += __shfl_down(m, off, 64);
    }
    const int wid  = threadIdx.x >> 6;
    const int lane = threadIdx.x & 63;
    if (lane == 0) { red_l[wid] = l; red_m[wid] = m; }
    __syncthreads();
    if (threadIdx.x == 0) {
        float L = 0.f, M = 0.f;
        #pragma unroll
        for (int w = 0; w < TPB / 64; ++w) { L += red_l[w]; M += red_m[w]; }
        partial[blockIdx.x] = make_float2(L, M);
    }
}

__global__ __launch_bounds__(256) void obb_finalize(
    const float2* __restrict__ partial, int nb, float* __restrict__ out)
{
    __shared__ double sl[256], sm[256];
    double l = 0.0, m = 0.0;
    for (int i = threadIdx.x; i < nb; i += 256) {
        const float2 v = partial[i];
        l += (double)v.x;
        m += (double)v.y;
    }
    sl[threadIdx.x] = l;
    sm[threadIdx.x] = m;
    __syncthreads();
    for (int s = 128; s > 0; s >>= 1) {
        if (threadIdx.x < s) {
            sl[threadIdx.x] += sl[threadIdx.x + s];
            sm[threadIdx.x] += sm[threadIdx.x + s];
        }
        __syncthreads();
    }
    if (threadIdx.x == 0) {
        const double nval = sm[0];
        const double mean = sl[0] / (nval > 1.0 ? nval : 1.0);
        out[0] = (nval > 0.0) ? (float)mean : 0.f;
    }
}

extern "C" void kernel_launch(void* const* d_in, const int* in_sizes, int n_in,
                              void* d_out, int out_size, void* d_ws, size_t ws_size,
                              hipStream_t stream)
{
    const float4* pred = (const float4*)d_in[0];   // (B,N,8) f32
    const float4* gt   = (const float4*)d_in[1];   // (B,N,8) f32
    const int* imsz    = (const int*)d_in[2];      // (B,2) i32
    const int* mask    = (const int*)d_in[3];      // (B,N) bool->i32
    float* out = (float*)d_out;                    // scalar f32

    const int total  = in_sizes[0] / 8;            // B*N
    const int B      = in_sizes[2] / 2;
    const int nper   = total / B;                  // N
    const int blocks = (total + TPB - 1) / TPB;

    float2* partial = (float2*)d_ws;               // blocks * 8 B

    obb_pair_kernel<<<blocks, TPB, 0, stream>>>(pred, gt, imsz, mask,
                                                partial, nper, total);
    obb_finalize<<<1, 256, 0, stream>>>(partial, blocks, out);
}